// Round 1
// baseline (1238.518 us; speedup 1.0000x reference)
//
#include <hip/hip_runtime.h>
#include <hip/hip_bf16.h>
#include <math.h>

#define BQ 2
#define QN 900
#define CD 256
#define NHH 8
#define NCC 6
#define NLL 3

// ---------------------------------------------------------------- elementwise add
__global__ __launch_bounds__(256) void add_kernel(const float* __restrict__ a,
                                                  const float* __restrict__ b,
                                                  float* __restrict__ out, int n) {
    int i = blockIdx.x * 256 + threadIdx.x;
    if (i < n) out[i] = a[i] + b[i];
}

// ---------------------------------------------------------------- generic tiled fp32 GEMM
// C[m, n] = act( sum_k A[m,k] * W[n,k] + bias[n] )   (W row-major (N,K))
#define GBM 64
#define GBN 64
#define GBK 16
__global__ __launch_bounds__(256) void gemm_kernel(const float* __restrict__ A,
                                                   const float* __restrict__ W,
                                                   const float* __restrict__ bias,
                                                   float* __restrict__ Cmat,
                                                   int M, int N, int K, int ldc,
                                                   int coloff, int act) {
    __shared__ float As[GBK][GBM + 1];
    __shared__ float Ws[GBK][GBN + 1];
    int bm = blockIdx.y * GBM;
    int bn = blockIdx.x * GBN;
    int tid = threadIdx.x;
    int tr = (tid / 16) * 4;
    int tc = (tid % 16) * 4;
    float acc[4][4] = {};
    for (int k0 = 0; k0 < K; k0 += GBK) {
        for (int t = tid; t < GBM * GBK; t += 256) {
            int i = t / GBK, kk = t % GBK;
            int gm = bm + i, gk = k0 + kk;
            As[kk][i] = (gm < M && gk < K) ? A[(size_t)gm * K + gk] : 0.f;
        }
        for (int t = tid; t < GBN * GBK; t += 256) {
            int j = t / GBK, kk = t % GBK;
            int gn = bn + j, gk = k0 + kk;
            Ws[kk][j] = (gn < N && gk < K) ? W[(size_t)gn * K + gk] : 0.f;
        }
        __syncthreads();
        #pragma unroll
        for (int kk = 0; kk < GBK; ++kk) {
            float a[4], w[4];
            #pragma unroll
            for (int i = 0; i < 4; ++i) a[i] = As[kk][tr + i];
            #pragma unroll
            for (int j = 0; j < 4; ++j) w[j] = Ws[kk][tc + j];
            #pragma unroll
            for (int i = 0; i < 4; ++i)
                #pragma unroll
                for (int j = 0; j < 4; ++j) acc[i][j] += a[i] * w[j];
        }
        __syncthreads();
    }
    for (int i = 0; i < 4; ++i) {
        int gm = bm + tr + i;
        if (gm >= M) continue;
        for (int j = 0; j < 4; ++j) {
            int gn = bn + tc + j;
            if (gn >= N) continue;
            float v = acc[i][j] + (bias ? bias[gn] : 0.f);
            if (act == 1) v = fmaxf(v, 0.f);
            Cmat[(size_t)gm * ldc + gn + coloff] = v;
        }
    }
}

// ---------------------------------------------------------------- attention (one block per (b,h,q))
__global__ __launch_bounds__(256) void attn_kernel(const float* __restrict__ qkv,
                                                   float* __restrict__ obuf) {
    int blk = blockIdx.x;
    int q = blk % QN;
    int bh = blk / QN;
    int h = bh % NHH;
    int b = bh / NHH;
    __shared__ float satt[QN];
    __shared__ float qrow[32];
    __shared__ float red[8][33];
    __shared__ float rt[4];
    int tid = threadIdx.x;
    int wave = tid >> 6, lane = tid & 63;
    const float* qkvb = qkv + (size_t)b * QN * 768;
    if (tid < 32) qrow[tid] = qkvb[(size_t)q * 768 + h * 32 + tid];
    __syncthreads();

    float lmax = -1e30f;
    for (int kk = tid; kk < QN; kk += 256) {
        const float* krow = qkvb + (size_t)kk * 768 + 256 + h * 32;
        float dot = 0.f;
        #pragma unroll
        for (int d = 0; d < 32; ++d) dot += qrow[d] * krow[d];
        dot *= 0.17677669529663687f; // 1/sqrt(32)
        satt[kk] = dot;
        lmax = fmaxf(lmax, dot);
    }
    #pragma unroll
    for (int off = 32; off >= 1; off >>= 1) lmax = fmaxf(lmax, __shfl_xor(lmax, off));
    if (lane == 0) rt[wave] = lmax;
    __syncthreads();
    lmax = fmaxf(fmaxf(rt[0], rt[1]), fmaxf(rt[2], rt[3]));

    float lsum = 0.f;
    for (int kk = tid; kk < QN; kk += 256) {
        float e = expf(satt[kk] - lmax);
        satt[kk] = e;
        lsum += e;
    }
    #pragma unroll
    for (int off = 32; off >= 1; off >>= 1) lsum += __shfl_xor(lsum, off);
    __syncthreads();
    if (lane == 0) rt[wave] = lsum;
    __syncthreads();
    float inv = 1.0f / (rt[0] + rt[1] + rt[2] + rt[3]);
    for (int kk = tid; kk < QN; kk += 256) satt[kk] *= inv;
    __syncthreads();

    // PV: thread t -> d = t&31, group g = t>>5 (8 groups over k)
    int d = tid & 31, g = tid >> 5;
    float part = 0.f;
    const float* vbase = qkvb + 512 + h * 32 + d;
    for (int kk = g; kk < QN; kk += 8) part += satt[kk] * vbase[(size_t)kk * 768];
    red[g][d] = part;
    __syncthreads();
    if (tid < 32) {
        float o = 0.f;
        #pragma unroll
        for (int g2 = 0; g2 < 8; ++g2) o += red[g2][tid];
        obuf[((size_t)b * QN + q) * CD + h * 32 + tid] = o;
    }
}

// ---------------------------------------------------------------- LayerNorm (row = block, col = thread), up to 3 summed inputs
__global__ __launch_bounds__(256) void ln_kernel(const float* __restrict__ a,
                                                 const float* __restrict__ b,
                                                 const float* __restrict__ c,
                                                 const float* __restrict__ g,
                                                 const float* __restrict__ bt,
                                                 float* __restrict__ out, int act) {
    int row = blockIdx.x;
    int tid = threadIdx.x;
    size_t idx = (size_t)row * CD + tid;
    float v = a[idx];
    if (b) v += b[idx];
    if (c) v += c[idx];
    __shared__ float rt[4];
    int wave = tid >> 6, lane = tid & 63;
    float s = v;
    #pragma unroll
    for (int off = 32; off >= 1; off >>= 1) s += __shfl_xor(s, off);
    if (lane == 0) rt[wave] = s;
    __syncthreads();
    float mu = (rt[0] + rt[1] + rt[2] + rt[3]) * (1.0f / 256.0f);
    float dv = v - mu;
    float s2 = dv * dv;
    #pragma unroll
    for (int off = 32; off >= 1; off >>= 1) s2 += __shfl_xor(s2, off);
    __syncthreads();
    if (lane == 0) rt[wave] = s2;
    __syncthreads();
    float var = (rt[0] + rt[1] + rt[2] + rt[3]) * (1.0f / 256.0f);
    float y = dv * rsqrtf(var + 1e-5f) * g[tid] + bt[tid];
    if (act == 1) y = fmaxf(y, 0.f);
    out[idx] = y;
}

// ---------------------------------------------------------------- camera projection + inv-sigmoid of ref points
__global__ __launch_bounds__(256) void proj_kernel(const float* __restrict__ ref,
                                                   const float* __restrict__ l2i,
                                                   float* __restrict__ grid,
                                                   float* __restrict__ maskb,
                                                   float* __restrict__ invref) {
    int i = blockIdx.x * 256 + threadIdx.x;
    if (i >= BQ * QN) return;
    int b = i / QN;
    int q = i % QN;
    const float eps = 1e-5f;
    float r[3];
    r[0] = ref[(size_t)i * 3 + 0];
    r[1] = ref[(size_t)i * 3 + 1];
    r[2] = ref[(size_t)i * 3 + 2];
    // inverse sigmoid
    #pragma unroll
    for (int d = 0; d < 3; ++d) {
        float num = fminf(fmaxf(r[d], eps), 1.0f);
        float den = fminf(fmaxf(1.0f - r[d], eps), 1.0f);
        invref[(size_t)i * 3 + d] = logf(num / den);
    }
    float X = r[0] * 102.4f - 51.2f;
    float Y = r[1] * 102.4f - 51.2f;
    float Z = r[2] * 8.0f - 5.0f;
    for (int n = 0; n < NCC; ++n) {
        const float* L = l2i + ((size_t)b * NCC + n) * 16;
        float c0 = L[0] * X + L[1] * Y + L[2] * Z + L[3];
        float c1 = L[4] * X + L[5] * Y + L[6] * Z + L[7];
        float c2 = L[8] * X + L[9] * Y + L[10] * Z + L[11];
        bool m = c2 > eps;
        float dz = fmaxf(c2, eps);
        float gx = (c0 / dz) / 1600.0f * 2.0f - 1.0f;
        float gy = (c1 / dz) / 928.0f * 2.0f - 1.0f;
        m = m && (gx > -1.0f) && (gx < 1.0f) && (gy > -1.0f) && (gy < 1.0f);
        size_t nq = ((size_t)b * NCC + n) * QN + q;
        grid[nq * 2 + 0] = gx;
        grid[nq * 2 + 1] = gy;
        maskb[nq] = m ? 1.0f : 0.0f;
    }
}

// ---------------------------------------------------------------- attention-weight head: sigmoid(x @ attW.T + attb) -> (B*Q, 18)
__global__ __launch_bounds__(192) void attw_kernel(const float* __restrict__ x,
                                                   const float* __restrict__ attW,
                                                   const float* __restrict__ attb,
                                                   float* __restrict__ aw) {
    int row = blockIdx.x;
    int tid = threadIdx.x;
    int j = tid >> 3, s = tid & 7;
    float p = 0.f;
    if (j < 18) {
        const float* xr = x + (size_t)row * CD;
        const float* wr = attW + (size_t)j * CD;
        for (int cc = s; cc < CD; cc += 8) p += xr[cc] * wr[cc];
    }
    #pragma unroll
    for (int off = 4; off >= 1; off >>= 1) p += __shfl_down(p, off, 8);
    if (j < 18 && s == 0) {
        float v = p + attb[j];
        aw[(size_t)row * 18 + j] = 1.0f / (1.0f + expf(-v));
    }
}

// ---------------------------------------------------------------- bilinear sample + weighted fusion (block per (b,q), thread per channel)
__global__ __launch_bounds__(256) void fusion_kernel(const float* __restrict__ feat0,
                                                     const float* __restrict__ feat1,
                                                     const float* __restrict__ feat2,
                                                     const float* __restrict__ grid,
                                                     const float* __restrict__ maskb,
                                                     const float* __restrict__ aw,
                                                     float* __restrict__ fused) {
    int i = blockIdx.x; // b*QN + q
    int c = threadIdx.x;
    int b = i / QN, q = i % QN;
    const int HS[3] = {116, 58, 29};
    const int WS[3] = {200, 100, 50};
    float acc = 0.f;
    for (int n = 0; n < NCC; ++n) {
        size_t nq = ((size_t)b * NCC + n) * QN + q;
        if (maskb[nq] == 0.f) continue;
        float gx = grid[nq * 2 + 0];
        float gy = grid[nq * 2 + 1];
        #pragma unroll
        for (int l = 0; l < NLL; ++l) {
            int H = HS[l], W = WS[l];
            const float* f = (l == 0) ? feat0 : ((l == 1) ? feat1 : feat2);
            float x = (gx + 1.0f) * 0.5f * (float)W - 0.5f;
            float y = (gy + 1.0f) * 0.5f * (float)H - 0.5f;
            float x0f = floorf(x), y0f = floorf(y);
            float wx = x - x0f, wy = y - y0f;
            int x0 = (int)x0f, y0 = (int)y0f;
            const float* fb = f + (((size_t)b * NCC + n) * CD + c) * (size_t)(H * W);
            float v00 = 0.f, v01 = 0.f, v10 = 0.f, v11 = 0.f;
            bool xv0 = (x0 >= 0) && (x0 < W);
            bool xv1 = (x0 + 1 >= 0) && (x0 + 1 < W);
            bool yv0 = (y0 >= 0) && (y0 < H);
            bool yv1 = (y0 + 1 >= 0) && (y0 + 1 < H);
            if (yv0) {
                if (xv0) v00 = fb[(size_t)y0 * W + x0];
                if (xv1) v01 = fb[(size_t)y0 * W + x0 + 1];
            }
            if (yv1) {
                if (xv0) v10 = fb[(size_t)(y0 + 1) * W + x0];
                if (xv1) v11 = fb[(size_t)(y0 + 1) * W + x0 + 1];
            }
            float sval = v00 * (1 - wx) * (1 - wy) + v01 * wx * (1 - wy) +
                         v10 * (1 - wx) * wy + v11 * wx * wy;
            acc += sval * aw[(size_t)i * 18 + n * 3 + l];
        }
    }
    fused[(size_t)i * CD + c] = acc;
}

// ================================================================ host
extern "C" void kernel_launch(void* const* d_in, const int* in_sizes, int n_in,
                              void* d_out, int out_size, void* d_ws, size_t ws_size,
                              hipStream_t stream) {
    const float* query    = (const float*)d_in[0];
    const float* querypos = (const float*)d_in[1];
    const float* refpts   = (const float*)d_in[2];
    const float* l2i      = (const float*)d_in[3];
    const float* feat0    = (const float*)d_in[4];
    const float* feat1    = (const float*)d_in[5];
    const float* feat2    = (const float*)d_in[6];
    const float* Wqkv     = (const float*)d_in[7];
    const float* bqkv     = (const float*)d_in[8];
    const float* Wo       = (const float*)d_in[9];
    const float* bo       = (const float*)d_in[10];
    const float* attW     = (const float*)d_in[11];
    const float* attb     = (const float*)d_in[12];
    const float* outW     = (const float*)d_in[13];
    const float* outbias  = (const float*)d_in[14];
    const float* peW1     = (const float*)d_in[15];
    const float* peb1     = (const float*)d_in[16];
    const float* peg1     = (const float*)d_in[17];
    const float* pebt1    = (const float*)d_in[18];
    const float* peW2     = (const float*)d_in[19];
    const float* peb2     = (const float*)d_in[20];
    const float* peg2     = (const float*)d_in[21];
    const float* pebt2    = (const float*)d_in[22];
    const float* ffW1     = (const float*)d_in[23];
    const float* ffb1     = (const float*)d_in[24];
    const float* ffW2     = (const float*)d_in[25];
    const float* ffb2     = (const float*)d_in[26];
    const float* n1g      = (const float*)d_in[27];
    const float* n1b      = (const float*)d_in[28];
    const float* n2g      = (const float*)d_in[29];
    const float* n2b      = (const float*)d_in[30];
    const float* n3g      = (const float*)d_in[31];
    const float* n3b      = (const float*)d_in[32];
    float* outp = (float*)d_out;

    const int M = BQ * QN;            // 1800
    const size_t NE = (size_t)M * CD; // 460800

    float* w = (float*)d_ws;
    size_t off = 0;
    auto alloc = [&](size_t n) { float* p = w + off; off += n; return p; };
    float* qbuf   = alloc(NE);
    float* qkv    = alloc((size_t)M * 768);
    float* obuf   = alloc(NE);
    float* sabuf  = alloc(NE);
    float* xbuf   = alloc(NE);
    float* gridb  = alloc((size_t)BQ * NCC * QN * 2);
    float* maskb  = alloc((size_t)BQ * NCC * QN);
    float* invref = alloc((size_t)M * 3);
    float* awb    = alloc((size_t)M * 18);
    float* fusedb = alloc(NE);
    float* outb_  = alloc(NE);
    float* pe1a   = alloc(NE);
    float* pe1    = alloc(NE);
    float* pe2a   = alloc(NE);
    float* pe2    = alloc(NE);
    float* x2buf  = alloc(NE);
    float* ffb    = alloc((size_t)M * 1024);
    float* ff2    = alloc(NE);
    (void)ws_size;

    dim3 blk256(256);

    // q = query + query_pos
    add_kernel<<<dim3((NE + 255) / 256), blk256, 0, stream>>>(query, querypos, qbuf, (int)NE);

    // qkv projections: [q|k] from qbuf, [v] from query
    gemm_kernel<<<dim3(512 / GBN, (M + GBM - 1) / GBM), blk256, 0, stream>>>(
        qbuf, Wqkv, bqkv, qkv, M, 512, CD, 768, 0, 0);
    gemm_kernel<<<dim3(256 / GBN, (M + GBM - 1) / GBM), blk256, 0, stream>>>(
        query, Wqkv + (size_t)512 * CD, bqkv + 512, qkv, M, 256, CD, 768, 512, 0);

    // attention
    attn_kernel<<<dim3(BQ * NHH * QN), blk256, 0, stream>>>(qkv, obuf);

    // out proj
    gemm_kernel<<<dim3(256 / GBN, (M + GBM - 1) / GBM), blk256, 0, stream>>>(
        obuf, Wo, bo, sabuf, M, 256, CD, 256, 0, 0);

    // x = LN(query + sa)
    ln_kernel<<<dim3(M), blk256, 0, stream>>>(query, sabuf, nullptr, n1g, n1b, xbuf, 0);

    // projection of reference points
    proj_kernel<<<dim3((M + 255) / 256), blk256, 0, stream>>>(refpts, l2i, gridb, maskb, invref);

    // attention weights
    attw_kernel<<<dim3(M), dim3(192), 0, stream>>>(xbuf, attW, attb, awb);

    // sampling + fusion
    fusion_kernel<<<dim3(M), blk256, 0, stream>>>(feat0, feat1, feat2, gridb, maskb, awb, fusedb);

    // out = fused @ outW.T + outb
    gemm_kernel<<<dim3(256 / GBN, (M + GBM - 1) / GBM), blk256, 0, stream>>>(
        fusedb, outW, outbias, outb_, M, 256, CD, 256, 0, 0);

    // position encoder
    gemm_kernel<<<dim3(256 / GBN, (M + GBM - 1) / GBM), blk256, 0, stream>>>(
        invref, peW1, peb1, pe1a, M, 256, 3, 256, 0, 0);
    ln_kernel<<<dim3(M), blk256, 0, stream>>>(pe1a, nullptr, nullptr, peg1, pebt1, pe1, 1);
    gemm_kernel<<<dim3(256 / GBN, (M + GBM - 1) / GBM), blk256, 0, stream>>>(
        pe1, peW2, peb2, pe2a, M, 256, CD, 256, 0, 0);
    ln_kernel<<<dim3(M), blk256, 0, stream>>>(pe2a, nullptr, nullptr, peg2, pebt2, pe2, 1);

    // x2 = LN(x + out + pe)
    ln_kernel<<<dim3(M), blk256, 0, stream>>>(xbuf, outb_, pe2, n2g, n2b, x2buf, 0);

    // FFN
    gemm_kernel<<<dim3(1024 / GBN, (M + GBM - 1) / GBM), blk256, 0, stream>>>(
        x2buf, ffW1, ffb1, ffb, M, 1024, CD, 1024, 0, 1);
    gemm_kernel<<<dim3(256 / GBN, (M + GBM - 1) / GBM), blk256, 0, stream>>>(
        ffb, ffW2, ffb2, ff2, M, 256, 1024, 256, 0, 0);

    // final LN -> d_out
    ln_kernel<<<dim3(M), blk256, 0, stream>>>(x2buf, ff2, nullptr, n3g, n3b, outp, 0);
}

// Round 2
// 767.018 us; speedup vs baseline: 1.6147x; 1.6147x over previous
//
#include <hip/hip_runtime.h>
#include <hip/hip_bf16.h>
#include <math.h>

#define BQ 2
#define QN 900
#define CD 256
#define NHH 8
#define NCC 6
#define NLL 3

// ---------------------------------------------------------------- generic tiled fp32 GEMM
// C[m, n] = act( sum_k (A[m,k]+A2[m,k]) * W[n,k] + bias[n] )   (W row-major (N,K))
#define BM 64
#define BN 64
#define BKK 32
__global__ __launch_bounds__(256) void gemm_kernel(const float* __restrict__ A,
                                                   const float* __restrict__ A2,
                                                   const float* __restrict__ W,
                                                   const float* __restrict__ bias,
                                                   float* __restrict__ Cmat,
                                                   int M, int N, int K, int ldc,
                                                   int coloff, int act) {
    __shared__ float As[BKK][BM + 4];
    __shared__ float Ws[BKK][BN + 4];
    int bm = blockIdx.y * BM;
    int bn = blockIdx.x * BN;
    int tid = threadIdx.x;
    int tr = (tid >> 4) * 4;
    int tc = (tid & 15) * 4;
    float acc[4][4] = {};
    for (int k0 = 0; k0 < K; k0 += BKK) {
        // A tile: BM x BKK, float4 along k, transposed into As[k][m]
        for (int e = tid; e < BM * BKK / 4; e += 256) {
            int row = e >> 3, kc = e & 7;
            int gm = bm + row, gk = k0 + kc * 4;
            float v0 = 0.f, v1 = 0.f, v2 = 0.f, v3 = 0.f;
            if (gm < M) {
                if (gk + 4 <= K) {
                    float4 v = *(const float4*)(A + (size_t)gm * K + gk);
                    if (A2) {
                        float4 w4 = *(const float4*)(A2 + (size_t)gm * K + gk);
                        v.x += w4.x; v.y += w4.y; v.z += w4.z; v.w += w4.w;
                    }
                    v0 = v.x; v1 = v.y; v2 = v.z; v3 = v.w;
                } else {
                    float t[4] = {0.f, 0.f, 0.f, 0.f};
                    for (int u = 0; u < 4; ++u)
                        if (gk + u < K) {
                            t[u] = A[(size_t)gm * K + gk + u];
                            if (A2) t[u] += A2[(size_t)gm * K + gk + u];
                        }
                    v0 = t[0]; v1 = t[1]; v2 = t[2]; v3 = t[3];
                }
            }
            As[kc * 4 + 0][row] = v0;
            As[kc * 4 + 1][row] = v1;
            As[kc * 4 + 2][row] = v2;
            As[kc * 4 + 3][row] = v3;
        }
        // W tile
        for (int e = tid; e < BN * BKK / 4; e += 256) {
            int row = e >> 3, kc = e & 7;
            int gn = bn + row, gk = k0 + kc * 4;
            float v0 = 0.f, v1 = 0.f, v2 = 0.f, v3 = 0.f;
            if (gn < N) {
                if (gk + 4 <= K) {
                    float4 v = *(const float4*)(W + (size_t)gn * K + gk);
                    v0 = v.x; v1 = v.y; v2 = v.z; v3 = v.w;
                } else {
                    for (int u = 0; u < 4; ++u)
                        if (gk + u < K) ((float*)&v0)[0] = 0.f; // keep simple below
                    float t[4] = {0.f, 0.f, 0.f, 0.f};
                    for (int u = 0; u < 4; ++u)
                        if (gk + u < K) t[u] = W[(size_t)gn * K + gk + u];
                    v0 = t[0]; v1 = t[1]; v2 = t[2]; v3 = t[3];
                }
            }
            Ws[kc * 4 + 0][row] = v0;
            Ws[kc * 4 + 1][row] = v1;
            Ws[kc * 4 + 2][row] = v2;
            Ws[kc * 4 + 3][row] = v3;
        }
        __syncthreads();
        #pragma unroll
        for (int kk = 0; kk < BKK; ++kk) {
            float4 a4 = *(const float4*)(&As[kk][tr]);
            float4 w4 = *(const float4*)(&Ws[kk][tc]);
            acc[0][0] += a4.x * w4.x; acc[0][1] += a4.x * w4.y; acc[0][2] += a4.x * w4.z; acc[0][3] += a4.x * w4.w;
            acc[1][0] += a4.y * w4.x; acc[1][1] += a4.y * w4.y; acc[1][2] += a4.y * w4.z; acc[1][3] += a4.y * w4.w;
            acc[2][0] += a4.z * w4.x; acc[2][1] += a4.z * w4.y; acc[2][2] += a4.z * w4.z; acc[2][3] += a4.z * w4.w;
            acc[3][0] += a4.w * w4.x; acc[3][1] += a4.w * w4.y; acc[3][2] += a4.w * w4.z; acc[3][3] += a4.w * w4.w;
        }
        __syncthreads();
    }
    float4 b4 = make_float4(0.f, 0.f, 0.f, 0.f);
    if (bias) b4 = *(const float4*)(&bias[bn + tc]);
    for (int i = 0; i < 4; ++i) {
        int gm = bm + tr + i;
        if (gm >= M) continue;
        float4 r;
        r.x = acc[i][0] + b4.x; r.y = acc[i][1] + b4.y;
        r.z = acc[i][2] + b4.z; r.w = acc[i][3] + b4.w;
        if (act == 1) {
            r.x = fmaxf(r.x, 0.f); r.y = fmaxf(r.y, 0.f);
            r.z = fmaxf(r.z, 0.f); r.w = fmaxf(r.w, 0.f);
        }
        *(float4*)(&Cmat[(size_t)gm * ldc + bn + tc + coloff]) = r;
    }
}

// ---------------------------------------------------------------- flash attention
// grid (29, 16): x = q-tile of 32 rows, y = b*8+h. 256 threads.
#define QT 32
#define KT 64
__global__ __launch_bounds__(256) void flash_kernel(const float* __restrict__ qkv,
                                                    float* __restrict__ obuf) {
    int qt = blockIdx.x;
    int bh = blockIdx.y;
    int h = bh & 7, b = bh >> 3;
    int tid = threadIdx.x;
    __shared__ float Qs[QT][36];
    __shared__ float Ks[KT][36];
    __shared__ float Vs[KT][36];
    __shared__ float Ps[QT][68];
    __shared__ float mrow[QT], lrow[QT], lsc[QT];

    const float* qkvb = qkv + (size_t)b * QN * 768;
    int q0 = qt * QT;

    {   // load Q tile (256 float4s, one per thread)
        int row = tid >> 3, c4 = tid & 7;
        int gq = q0 + row;
        float4 v = make_float4(0.f, 0.f, 0.f, 0.f);
        if (gq < QN) v = *(const float4*)(qkvb + (size_t)gq * 768 + h * 32 + c4 * 4);
        *(float4*)(&Qs[row][c4 * 4]) = v;
    }
    if (tid < QT) { mrow[tid] = -1e30f; lrow[tid] = 0.f; }

    int grp = tid >> 4;      // 16 groups
    int r0 = grp * 2;        // rows r0, r0+1
    int cc = tid & 15;       // cols cc + 16*j
    int pr = tid >> 3;       // PV row 0..31
    int pd = (tid & 7) * 4;  // PV dcol
    float acc[4] = {0.f, 0.f, 0.f, 0.f};

    const int NT = (QN + KT - 1) / KT;
    for (int kt = 0; kt < NT; ++kt) {
        __syncthreads();
        {   // load K,V tiles
            int row = tid >> 3, c4 = tid & 7;
            #pragma unroll
            for (int half = 0; half < 2; ++half) {
                int rr = row + half * 32;
                int gk = kt * KT + rr;
                float4 kv = make_float4(0.f, 0.f, 0.f, 0.f);
                float4 vv = make_float4(0.f, 0.f, 0.f, 0.f);
                if (gk < QN) {
                    const float* base = qkvb + (size_t)gk * 768 + h * 32 + c4 * 4;
                    kv = *(const float4*)(base + 256);
                    vv = *(const float4*)(base + 512);
                }
                *(float4*)(&Ks[rr][c4 * 4]) = kv;
                *(float4*)(&Vs[rr][c4 * 4]) = vv;
            }
        }
        __syncthreads();
        // QK^T -> s[2][4]
        float s[2][4] = {};
        #pragma unroll
        for (int d4 = 0; d4 < 8; ++d4) {
            float4 qa = *(const float4*)(&Qs[r0][d4 * 4]);
            float4 qb = *(const float4*)(&Qs[r0 + 1][d4 * 4]);
            #pragma unroll
            for (int j = 0; j < 4; ++j) {
                float4 k4 = *(const float4*)(&Ks[cc + 16 * j][d4 * 4]);
                s[0][j] += qa.x * k4.x + qa.y * k4.y + qa.z * k4.z + qa.w * k4.w;
                s[1][j] += qb.x * k4.x + qb.y * k4.y + qb.z * k4.z + qb.w * k4.w;
            }
        }
        #pragma unroll
        for (int i = 0; i < 2; ++i)
            #pragma unroll
            for (int j = 0; j < 4; ++j) {
                int kg = kt * KT + cc + 16 * j;
                s[i][j] = (kg < QN) ? s[i][j] * 0.17677669529663687f : -1e30f;
            }
        // online max update
        #pragma unroll
        for (int i = 0; i < 2; ++i) {
            float tm = fmaxf(fmaxf(s[i][0], s[i][1]), fmaxf(s[i][2], s[i][3]));
            #pragma unroll
            for (int off = 8; off >= 1; off >>= 1) tm = fmaxf(tm, __shfl_xor(tm, off));
            if (cc == 0) {
                float mo = mrow[r0 + i];
                float mn = fmaxf(mo, tm);
                lsc[r0 + i] = __expf(mo - mn);
                mrow[r0 + i] = mn;
            }
        }
        __syncthreads();
        // P = exp(s - m); write Ps; update l
        #pragma unroll
        for (int i = 0; i < 2; ++i) {
            float m = mrow[r0 + i];
            float rs = 0.f;
            #pragma unroll
            for (int j = 0; j < 4; ++j) {
                float p = __expf(s[i][j] - m);
                Ps[r0 + i][cc + 16 * j] = p;
                rs += p;
            }
            #pragma unroll
            for (int off = 8; off >= 1; off >>= 1) rs += __shfl_xor(rs, off);
            if (cc == 0) lrow[r0 + i] = lrow[r0 + i] * lsc[r0 + i] + rs;
        }
        // rescale O fragment
        float sc = lsc[pr];
        #pragma unroll
        for (int j = 0; j < 4; ++j) acc[j] *= sc;
        __syncthreads();
        // PV accumulate
        #pragma unroll 4
        for (int k = 0; k < KT; ++k) {
            float p = Ps[pr][k];
            float4 v4 = *(const float4*)(&Vs[k][pd]);
            acc[0] += p * v4.x; acc[1] += p * v4.y;
            acc[2] += p * v4.z; acc[3] += p * v4.w;
        }
    }
    __syncthreads();
    int gq = q0 + pr;
    if (gq < QN) {
        float inv = 1.0f / lrow[pr];
        float* op = obuf + ((size_t)b * QN + gq) * CD + h * 32 + pd;
        op[0] = acc[0] * inv; op[1] = acc[1] * inv;
        op[2] = acc[2] * inv; op[3] = acc[3] * inv;
    }
}

// ---------------------------------------------------------------- LayerNorm (row = block, col = thread), up to 3 summed inputs
__global__ __launch_bounds__(256) void ln_kernel(const float* __restrict__ a,
                                                 const float* __restrict__ b,
                                                 const float* __restrict__ c,
                                                 const float* __restrict__ g,
                                                 const float* __restrict__ bt,
                                                 float* __restrict__ out, int act) {
    int row = blockIdx.x;
    int tid = threadIdx.x;
    size_t idx = (size_t)row * CD + tid;
    float v = a[idx];
    if (b) v += b[idx];
    if (c) v += c[idx];
    __shared__ float rt[4];
    int wave = tid >> 6, lane = tid & 63;
    float s = v;
    #pragma unroll
    for (int off = 32; off >= 1; off >>= 1) s += __shfl_xor(s, off);
    if (lane == 0) rt[wave] = s;
    __syncthreads();
    float mu = (rt[0] + rt[1] + rt[2] + rt[3]) * (1.0f / 256.0f);
    float dv = v - mu;
    float s2 = dv * dv;
    #pragma unroll
    for (int off = 32; off >= 1; off >>= 1) s2 += __shfl_xor(s2, off);
    __syncthreads();
    if (lane == 0) rt[wave] = s2;
    __syncthreads();
    float var = (rt[0] + rt[1] + rt[2] + rt[3]) * (1.0f / 256.0f);
    float y = dv * rsqrtf(var + 1e-5f) * g[tid] + bt[tid];
    if (act == 1) y = fmaxf(y, 0.f);
    out[idx] = y;
}

// ---------------------------------------------------------------- camera projection + inv-sigmoid of ref points
__global__ __launch_bounds__(256) void proj_kernel(const float* __restrict__ ref,
                                                   const float* __restrict__ l2i,
                                                   float* __restrict__ grid,
                                                   float* __restrict__ maskb,
                                                   float* __restrict__ invref) {
    int i = blockIdx.x * 256 + threadIdx.x;
    if (i >= BQ * QN) return;
    int b = i / QN;
    int q = i % QN;
    const float eps = 1e-5f;
    float r[3];
    r[0] = ref[(size_t)i * 3 + 0];
    r[1] = ref[(size_t)i * 3 + 1];
    r[2] = ref[(size_t)i * 3 + 2];
    #pragma unroll
    for (int d = 0; d < 3; ++d) {
        float num = fminf(fmaxf(r[d], eps), 1.0f);
        float den = fminf(fmaxf(1.0f - r[d], eps), 1.0f);
        invref[(size_t)i * 3 + d] = logf(num / den);
    }
    float X = r[0] * 102.4f - 51.2f;
    float Y = r[1] * 102.4f - 51.2f;
    float Z = r[2] * 8.0f - 5.0f;
    for (int n = 0; n < NCC; ++n) {
        const float* L = l2i + ((size_t)b * NCC + n) * 16;
        float c0 = L[0] * X + L[1] * Y + L[2] * Z + L[3];
        float c1 = L[4] * X + L[5] * Y + L[6] * Z + L[7];
        float c2 = L[8] * X + L[9] * Y + L[10] * Z + L[11];
        bool m = c2 > eps;
        float dz = fmaxf(c2, eps);
        float gx = (c0 / dz) / 1600.0f * 2.0f - 1.0f;
        float gy = (c1 / dz) / 928.0f * 2.0f - 1.0f;
        m = m && (gx > -1.0f) && (gx < 1.0f) && (gy > -1.0f) && (gy < 1.0f);
        size_t nq = ((size_t)b * NCC + n) * QN + q;
        grid[nq * 2 + 0] = gx;
        grid[nq * 2 + 1] = gy;
        maskb[nq] = m ? 1.0f : 0.0f;
    }
}

// ---------------------------------------------------------------- attention-weight head
__global__ __launch_bounds__(192) void attw_kernel(const float* __restrict__ x,
                                                   const float* __restrict__ attW,
                                                   const float* __restrict__ attb,
                                                   float* __restrict__ aw) {
    int row = blockIdx.x;
    int tid = threadIdx.x;
    int j = tid >> 3, s = tid & 7;
    float p = 0.f;
    if (j < 18) {
        const float* xr = x + (size_t)row * CD;
        const float* wr = attW + (size_t)j * CD;
        for (int cc = s; cc < CD; cc += 8) p += xr[cc] * wr[cc];
    }
    #pragma unroll
    for (int off = 4; off >= 1; off >>= 1) p += __shfl_down(p, off, 8);
    if (j < 18 && s == 0) {
        float v = p + attb[j];
        aw[(size_t)row * 18 + j] = 1.0f / (1.0f + expf(-v));
    }
}

// ---------------------------------------------------------------- bilinear sample + weighted fusion
__global__ __launch_bounds__(256) void fusion_kernel(const float* __restrict__ feat0,
                                                     const float* __restrict__ feat1,
                                                     const float* __restrict__ feat2,
                                                     const float* __restrict__ grid,
                                                     const float* __restrict__ maskb,
                                                     const float* __restrict__ aw,
                                                     float* __restrict__ fused) {
    int i = blockIdx.x; // b*QN + q
    int c = threadIdx.x;
    int b = i / QN, q = i % QN;
    const int HS[3] = {116, 58, 29};
    const int WS[3] = {200, 100, 50};
    float acc = 0.f;
    for (int n = 0; n < NCC; ++n) {
        size_t nq = ((size_t)b * NCC + n) * QN + q;
        if (maskb[nq] == 0.f) continue;
        float gx = grid[nq * 2 + 0];
        float gy = grid[nq * 2 + 1];
        #pragma unroll
        for (int l = 0; l < NLL; ++l) {
            int H = HS[l], W = WS[l];
            const float* f = (l == 0) ? feat0 : ((l == 1) ? feat1 : feat2);
            float x = (gx + 1.0f) * 0.5f * (float)W - 0.5f;
            float y = (gy + 1.0f) * 0.5f * (float)H - 0.5f;
            float x0f = floorf(x), y0f = floorf(y);
            float wx = x - x0f, wy = y - y0f;
            int x0 = (int)x0f, y0 = (int)y0f;
            const float* fb = f + (((size_t)b * NCC + n) * CD + c) * (size_t)(H * W);
            float v00 = 0.f, v01 = 0.f, v10 = 0.f, v11 = 0.f;
            bool xv0 = (x0 >= 0) && (x0 < W);
            bool xv1 = (x0 + 1 >= 0) && (x0 + 1 < W);
            bool yv0 = (y0 >= 0) && (y0 < H);
            bool yv1 = (y0 + 1 >= 0) && (y0 + 1 < H);
            if (yv0) {
                if (xv0) v00 = fb[(size_t)y0 * W + x0];
                if (xv1) v01 = fb[(size_t)y0 * W + x0 + 1];
            }
            if (yv1) {
                if (xv0) v10 = fb[(size_t)(y0 + 1) * W + x0];
                if (xv1) v11 = fb[(size_t)(y0 + 1) * W + x0 + 1];
            }
            float sval = v00 * (1 - wx) * (1 - wy) + v01 * wx * (1 - wy) +
                         v10 * (1 - wx) * wy + v11 * wx * wy;
            acc += sval * aw[(size_t)i * 18 + n * 3 + l];
        }
    }
    fused[(size_t)i * CD + c] = acc;
}

// ================================================================ host
extern "C" void kernel_launch(void* const* d_in, const int* in_sizes, int n_in,
                              void* d_out, int out_size, void* d_ws, size_t ws_size,
                              hipStream_t stream) {
    const float* query    = (const float*)d_in[0];
    const float* querypos = (const float*)d_in[1];
    const float* refpts   = (const float*)d_in[2];
    const float* l2i      = (const float*)d_in[3];
    const float* feat0    = (const float*)d_in[4];
    const float* feat1    = (const float*)d_in[5];
    const float* feat2    = (const float*)d_in[6];
    const float* Wqkv     = (const float*)d_in[7];
    const float* bqkv     = (const float*)d_in[8];
    const float* Wo       = (const float*)d_in[9];
    const float* bo       = (const float*)d_in[10];
    const float* attW     = (const float*)d_in[11];
    const float* attb     = (const float*)d_in[12];
    const float* outW     = (const float*)d_in[13];
    const float* outbias  = (const float*)d_in[14];
    const float* peW1     = (const float*)d_in[15];
    const float* peb1     = (const float*)d_in[16];
    const float* peg1     = (const float*)d_in[17];
    const float* pebt1    = (const float*)d_in[18];
    const float* peW2     = (const float*)d_in[19];
    const float* peb2     = (const float*)d_in[20];
    const float* peg2     = (const float*)d_in[21];
    const float* pebt2    = (const float*)d_in[22];
    const float* ffW1     = (const float*)d_in[23];
    const float* ffb1     = (const float*)d_in[24];
    const float* ffW2     = (const float*)d_in[25];
    const float* ffb2     = (const float*)d_in[26];
    const float* n1g      = (const float*)d_in[27];
    const float* n1b      = (const float*)d_in[28];
    const float* n2g      = (const float*)d_in[29];
    const float* n2b      = (const float*)d_in[30];
    const float* n3g      = (const float*)d_in[31];
    const float* n3b      = (const float*)d_in[32];
    float* outp = (float*)d_out;

    const int M = BQ * QN;            // 1800
    const size_t NE = (size_t)M * CD; // 460800

    float* w = (float*)d_ws;
    size_t off = 0;
    auto alloc = [&](size_t n) { float* p = w + off; off += n; return p; };
    float* qkv    = alloc((size_t)M * 768);
    float* obuf   = alloc(NE);
    float* sabuf  = alloc(NE);
    float* xbuf   = alloc(NE);
    float* gridb  = alloc((size_t)BQ * NCC * QN * 2);
    float* maskb  = alloc((size_t)BQ * NCC * QN);
    float* invref = alloc((size_t)M * 3);
    float* awb    = alloc((size_t)M * 18);
    float* fusedb = alloc(NE);
    float* outb_  = alloc(NE);
    float* pe1a   = alloc(NE);
    float* pe1    = alloc(NE);
    float* pe2a   = alloc(NE);
    float* pe2    = alloc(NE);
    float* x2buf  = alloc(NE);
    float* ffb    = alloc((size_t)M * 1024);
    float* ff2    = alloc(NE);
    (void)ws_size;

    dim3 blk256(256);
    int mb = (M + BM - 1) / BM; // 29

    // qkv projections: [q|k] from (query+querypos), [v] from query
    gemm_kernel<<<dim3(512 / BN, mb), blk256, 0, stream>>>(
        query, querypos, Wqkv, bqkv, qkv, M, 512, CD, 768, 0, 0);
    gemm_kernel<<<dim3(256 / BN, mb), blk256, 0, stream>>>(
        query, nullptr, Wqkv + (size_t)512 * CD, bqkv + 512, qkv, M, 256, CD, 768, 512, 0);

    // flash attention
    flash_kernel<<<dim3((QN + QT - 1) / QT, BQ * NHH), blk256, 0, stream>>>(qkv, obuf);

    // out proj
    gemm_kernel<<<dim3(256 / BN, mb), blk256, 0, stream>>>(
        obuf, nullptr, Wo, bo, sabuf, M, 256, CD, 256, 0, 0);

    // x = LN(query + sa)
    ln_kernel<<<dim3(M), blk256, 0, stream>>>(query, sabuf, nullptr, n1g, n1b, xbuf, 0);

    // projection of reference points
    proj_kernel<<<dim3((M + 255) / 256), blk256, 0, stream>>>(refpts, l2i, gridb, maskb, invref);

    // attention weights
    attw_kernel<<<dim3(M), dim3(192), 0, stream>>>(xbuf, attW, attb, awb);

    // sampling + fusion
    fusion_kernel<<<dim3(M), blk256, 0, stream>>>(feat0, feat1, feat2, gridb, maskb, awb, fusedb);

    // out = fused @ outW.T + outb
    gemm_kernel<<<dim3(256 / BN, mb), blk256, 0, stream>>>(
        fusedb, nullptr, outW, outbias, outb_, M, 256, CD, 256, 0, 0);

    // position encoder
    gemm_kernel<<<dim3(256 / BN, mb), blk256, 0, stream>>>(
        invref, nullptr, peW1, peb1, pe1a, M, 256, 3, 256, 0, 0);
    ln_kernel<<<dim3(M), blk256, 0, stream>>>(pe1a, nullptr, nullptr, peg1, pebt1, pe1, 1);
    gemm_kernel<<<dim3(256 / BN, mb), blk256, 0, stream>>>(
        pe1, nullptr, peW2, peb2, pe2a, M, 256, CD, 256, 0, 0);
    ln_kernel<<<dim3(M), blk256, 0, stream>>>(pe2a, nullptr, nullptr, peg2, pebt2, pe2, 1);

    // x2 = LN(x + out + pe)
    ln_kernel<<<dim3(M), blk256, 0, stream>>>(xbuf, outb_, pe2, n2g, n2b, x2buf, 0);

    // FFN
    gemm_kernel<<<dim3(1024 / BN, mb), blk256, 0, stream>>>(
        x2buf, nullptr, ffW1, ffb1, ffb, M, 1024, CD, 1024, 0, 1);
    gemm_kernel<<<dim3(256 / BN, mb), blk256, 0, stream>>>(
        ffb, nullptr, ffW2, ffb2, ff2, M, 256, 1024, 256, 0, 0);

    // final LN -> d_out
    ln_kernel<<<dim3(M), blk256, 0, stream>>>(x2buf, ff2, nullptr, n3g, n3b, outp, 0);
}